// Round 14
// baseline (963.865 us; speedup 1.0000x reference)
//
#include <hip/hip_runtime.h>

// 2-layer GCN, bucket-LDS-aggregate, bf16 payloads, zero global atomics.
//   hist -> scan1 -> scan2 -> [scatter ∥ gemm, 1:1] -> degscale -> agg1 -> agg2f
// R14: counting sort + csr + per-node gathers ELIMINATED.  Edges stay grouped
// by 256-node bucket; per-bucket kernels accumulate h[src] rows directly into
// an LDS fp32 accumulator (stride 17 -> random-bank spread, ~2-way = free).
// This does exactly E scattered 32B row-reads (the old clamped gathers did ~2x)
// with 2 lanes x uint4 per row (16x fewer load instrs than R11 gathers).
// R13 lesson: small gemm slices underfill the machine -> single 1:1
// scatter∥gemm pairing (R11 form) kept for the whole gemm.

#define TPB 256
#define CHUNK 4096          // edges per hist/scatter block (1:1 with gemm blocks)
#define BK_SHIFT 8
#define NPB 256             // nodes per bucket

__device__ __forceinline__ float bf2f(unsigned short u) {
    union { unsigned int i; float f; } v; v.i = ((unsigned int)u) << 16; return v.f;
}
__device__ __forceinline__ unsigned short f2bf(float f) {
    union { float f; unsigned int i; } v; v.f = f;
    unsigned int r = v.i + 0x7fff + ((v.i >> 16) & 1);   // RNE
    return (unsigned short)(r >> 16);
}

// hist: counts[bk*nblk + blk] = #edges in chunk blk with col>>8 == bk
__global__ __launch_bounds__(TPB) void hist_kernel(const int* __restrict__ col,
                                                   int* __restrict__ counts,
                                                   int E, int nblk, int nbuck) {
    __shared__ int hist[1024];
    int t = threadIdx.x;
    for (int i = t; i < nbuck; i += TPB) hist[i] = 0;
    __syncthreads();
    int e0 = blockIdx.x * CHUNK;
    for (int i = t; i < CHUNK; i += TPB) {
        int e = e0 + i;
        if (e < E) atomicAdd(&hist[col[e] >> BK_SHIFT], 1);   // LDS atomic
    }
    __syncthreads();
    for (int i = t; i < nbuck; i += TPB) counts[i * nblk + blockIdx.x] = hist[i];
}

// scan1: per-256-block exclusive scan (counts in place), bsum[b]=block total
__global__ __launch_bounds__(TPB) void scan1_kernel(int* __restrict__ counts,
                                                    int* __restrict__ bsum, int L) {
    __shared__ int s[TPB];
    int t = threadIdx.x;
    int i = blockIdx.x * TPB + t;
    int d = (i < L) ? counts[i] : 0;
    s[t] = d; __syncthreads();
    for (int off = 1; off < TPB; off <<= 1) {
        int v = (t >= off) ? s[t - off] : 0;
        __syncthreads();
        s[t] += v;
        __syncthreads();
    }
    if (i < L) counts[i] = s[t] - d;
    if (t == TPB - 1) bsum[blockIdx.x] = s[t];
}

// scan2: single-block exclusive scan of up to 4096 block sums (4 elems/thread)
__global__ __launch_bounds__(1024) void scan2_kernel(int* __restrict__ bsum, int nb) {
    __shared__ int s[1024];
    int t = threadIdx.x;
    int base = t * 4;
    int v[4], pv = 0;
#pragma unroll
    for (int u = 0; u < 4; ++u) {
        v[u] = (base + u < nb) ? bsum[base + u] : 0;
        pv += v[u];
    }
    s[t] = pv; __syncthreads();
    for (int off = 1; off < 1024; off <<= 1) {
        int u = (t >= off) ? s[t - off] : 0;
        __syncthreads();
        s[t] += u;
        __syncthreads();
    }
    int exc = s[t] - pv;
#pragma unroll
    for (int u = 0; u < 4; ++u) {
        if (base + u < nb) bsum[base + u] = exc;
        exc += v[u];
    }
}

// cbase[f] = counts[f] + bsum[f>>8]
__device__ __forceinline__ int cbase_at(const int* counts, const int* bsum, int f) {
    return counts[f] + bsum[f >> 8];
}

// scatter ∥ gemm, block-interleaved 1:1 (R11 form).
// Scatter: bucketed[pos] = (local_col<<18)|row.  Gemm: h1b = bf16(x@W1).
__global__ __launch_bounds__(TPB) void s1c_gemm_kernel(
        const int* __restrict__ row, const int* __restrict__ col,
        const int* __restrict__ counts, const int* __restrict__ bsum,
        int E, int nblk, int nbuck,
        int* __restrict__ bucketed,
        const float* __restrict__ x, const float* __restrict__ W1,
        unsigned short* __restrict__ h1b, int N, int nbg) {
    __shared__ int cur[1024];
    __shared__ float w1s[128 * 16];
    int b = (int)blockIdx.x, t = threadIdx.x;
    int M = min(nblk, nbg);
    int role, id;
    if (b < 2 * M) { role = b & 1; id = b >> 1; }
    else           { role = (nblk > nbg) ? 0 : 1; id = b - M; }

    if (role == 0) {                         // scatter
        for (int i = t; i < nbuck; i += TPB)
            cur[i] = cbase_at(counts, bsum, i * nblk + id);
        __syncthreads();
        int e0 = id * CHUNK;
        for (int i = t; i < CHUNK; i += TPB) {
            int e = e0 + i;
            if (e < E) {
                int c = col[e];
                int pos = atomicAdd(&cur[c >> BK_SHIFT], 1);   // LDS atomic
                bucketed[pos] = ((c & (NPB - 1)) << 18) | row[e];
            }
        }
        return;
    }
    // gemm
    for (int i = t; i < 128 * 16; i += TPB) w1s[i] = W1[i];
    __syncthreads();
    int n = id * TPB + t;
    if (n >= N) return;
    const float4* xr = (const float4*)(x + (size_t)n * 128);
    float acc[16];
#pragma unroll
    for (int k = 0; k < 16; ++k) acc[k] = 0.f;
#pragma unroll 1
    for (int g = 0; g < 8; ++g) {
        float4 v0 = xr[g * 4 + 0], v1 = xr[g * 4 + 1];
        float4 v2 = xr[g * 4 + 2], v3 = xr[g * 4 + 3];
        float xv[16] = {v0.x, v0.y, v0.z, v0.w, v1.x, v1.y, v1.z, v1.w,
                        v2.x, v2.y, v2.z, v2.w, v3.x, v3.y, v3.z, v3.w};
#pragma unroll
        for (int cc = 0; cc < 16; ++cc) {
            const float4* w4 = (const float4*)&w1s[(g * 16 + cc) * 16];
            float4 wa = w4[0], wb = w4[1], wc = w4[2], wd = w4[3];
            float xc = xv[cc];
            acc[0]  = fmaf(xc, wa.x, acc[0]);  acc[1]  = fmaf(xc, wa.y, acc[1]);
            acc[2]  = fmaf(xc, wa.z, acc[2]);  acc[3]  = fmaf(xc, wa.w, acc[3]);
            acc[4]  = fmaf(xc, wb.x, acc[4]);  acc[5]  = fmaf(xc, wb.y, acc[5]);
            acc[6]  = fmaf(xc, wb.z, acc[6]);  acc[7]  = fmaf(xc, wb.w, acc[7]);
            acc[8]  = fmaf(xc, wc.x, acc[8]);  acc[9]  = fmaf(xc, wc.y, acc[9]);
            acc[10] = fmaf(xc, wc.z, acc[10]); acc[11] = fmaf(xc, wc.w, acc[11]);
            acc[12] = fmaf(xc, wd.x, acc[12]); acc[13] = fmaf(xc, wd.y, acc[13]);
            acc[14] = fmaf(xc, wd.z, acc[14]); acc[15] = fmaf(xc, wd.w, acc[15]);
        }
    }
    unsigned int u[8];
#pragma unroll
    for (int j = 0; j < 8; ++j)
        u[j] = (unsigned int)f2bf(acc[2 * j]) | ((unsigned int)f2bf(acc[2 * j + 1]) << 16);
    uint4* o = (uint4*)(h1b + (size_t)n * 16);
    o[0] = make_uint4(u[0], u[1], u[2], u[3]);
    o[1] = make_uint4(u[4], u[5], u[6], u[7]);
}

// degscale: one block per bucket.  deg from LDS hist of the bucket's edges;
// dinv[n] = rsqrt(deg+1); h1p = bf16(dinv * h1b)  (coalesced).
__global__ __launch_bounds__(TPB) void degscale_kernel(
        const int* __restrict__ bucketed,
        const int* __restrict__ counts, const int* __restrict__ bsum,
        int E, int nblk, int nbuck,
        float* __restrict__ dinv,
        const unsigned short* __restrict__ h1b, unsigned short* __restrict__ h1p, int N) {
    __shared__ int lhist[NPB];
    __shared__ float sdinv[NPB];
    int bk = blockIdx.x, t = threadIdx.x;
    int n0 = bk << BK_SHIFT;
    int nn = min(NPB, N - n0);
    int e0 = cbase_at(counts, bsum, bk * nblk);
    int e1 = (bk + 1 < nbuck) ? cbase_at(counts, bsum, (bk + 1) * nblk) : E;

    lhist[t] = 0;
    __syncthreads();
    for (int i = e0 + t; i < e1; i += TPB)
        atomicAdd(&lhist[bucketed[i] >> 18], 1);               // LDS atomic
    __syncthreads();
    float dv = rsqrtf((float)lhist[t] + 1.0f);
    sdinv[t] = dv;
    if (t < nn) dinv[n0 + t] = dv;
    __syncthreads();

    const uint2* src = (const uint2*)h1b;                      // 4 feats per uint2
    uint2* dst = (uint2*)h1p;
    for (int i = t; i < nn * 4; i += TPB) {
        float d = sdinv[i >> 2];
        uint2 u = src[(size_t)n0 * 4 + i];
        float f0 = bf2f((unsigned short)(u.x & 0xffff)) * d;
        float f1 = bf2f((unsigned short)(u.x >> 16)) * d;
        float f2 = bf2f((unsigned short)(u.y & 0xffff)) * d;
        float f3 = bf2f((unsigned short)(u.y >> 16)) * d;
        uint2 w;
        w.x = (unsigned int)f2bf(f0) | ((unsigned int)f2bf(f1) << 16);
        w.y = (unsigned int)f2bf(f2) | ((unsigned int)f2bf(f3) << 16);
        dst[(size_t)n0 * 4 + i] = w;
    }
}

// shared edge-aggregation body: accumulate h[src] rows into acc[col*17 + k].
// 2 lanes per edge (uint4 = 8 bf16 feats each), unroll 4 -> 4 row-loads in flight.
__device__ __forceinline__ void agg_edges(const int* __restrict__ bucketed,
                                          const unsigned short* __restrict__ h,
                                          float* acc, int e0, int e1, int t) {
    int h2 = t & 1;                          // which half-row
    for (int i0 = e0 + (t >> 1); i0 < e1; i0 += 512) {
        int ent[4]; uint4 val[4]; bool ok[4];
#pragma unroll
        for (int u = 0; u < 4; ++u) {
            int i = i0 + u * 128;
            ok[u] = i < e1;
            ent[u] = bucketed[ok[u] ? i : e0];
        }
#pragma unroll
        for (int u = 0; u < 4; ++u) {
            int src = ent[u] & 0x3FFFF;
            val[u] = ((const uint4*)h)[(size_t)src * 2 + h2];
        }
#pragma unroll
        for (int u = 0; u < 4; ++u) {
            if (ok[u]) {
                float* a = &acc[(ent[u] >> 18) * 17 + h2 * 8];
                atomicAdd(a + 0, bf2f((unsigned short)(val[u].x & 0xffff)));
                atomicAdd(a + 1, bf2f((unsigned short)(val[u].x >> 16)));
                atomicAdd(a + 2, bf2f((unsigned short)(val[u].y & 0xffff)));
                atomicAdd(a + 3, bf2f((unsigned short)(val[u].y >> 16)));
                atomicAdd(a + 4, bf2f((unsigned short)(val[u].z & 0xffff)));
                atomicAdd(a + 5, bf2f((unsigned short)(val[u].z >> 16)));
                atomicAdd(a + 6, bf2f((unsigned short)(val[u].w & 0xffff)));
                atomicAdd(a + 7, bf2f((unsigned short)(val[u].w >> 16)));
            }
        }
    }
}

// agg1: one block per bucket.  acc = sum h1p[src]; then
// h2p[c] = bf16( dinv[c]*relu( dinv[c]*(acc + h1p[c]) + b1 ) )
__global__ __launch_bounds__(TPB) void agg1_kernel(
        const int* __restrict__ bucketed,
        const int* __restrict__ counts, const int* __restrict__ bsum,
        int E, int nblk, int nbuck,
        const unsigned short* __restrict__ h1p, const float* __restrict__ dinv,
        const float* __restrict__ b1, unsigned short* __restrict__ h2p, int N) {
    __shared__ float acc[NPB * 17];
    int bk = blockIdx.x, t = threadIdx.x;
    int n0 = bk << BK_SHIFT;
    int nn = min(NPB, N - n0);
    int e0 = cbase_at(counts, bsum, bk * nblk);
    int e1 = (bk + 1 < nbuck) ? cbase_at(counts, bsum, (bk + 1) * nblk) : E;

    for (int i = t; i < NPB * 17; i += TPB) acc[i] = 0.f;
    __syncthreads();
    agg_edges(bucketed, h1p, acc, e0, e1, t);
    __syncthreads();

    // epilogue: one uint (2 feats) per thread-slot
    for (int i = t; i < nn * 8; i += TPB) {
        int m = i >> 3, q = i & 7;           // feats 2q, 2q+1
        int c = n0 + m;
        float dc = dinv[c];
        unsigned int us = *(const unsigned int*)&h1p[(size_t)c * 16 + 2 * q];
        float a0 = acc[m * 17 + 2 * q]     + bf2f((unsigned short)(us & 0xffff));
        float a1 = acc[m * 17 + 2 * q + 1] + bf2f((unsigned short)(us >> 16));
        float r0 = dc * fmaxf(fmaf(dc, a0, b1[2 * q]), 0.f);
        float r1 = dc * fmaxf(fmaf(dc, a1, b1[2 * q + 1]), 0.f);
        *(unsigned int*)&h2p[(size_t)c * 16 + 2 * q] =
            (unsigned int)f2bf(r0) | ((unsigned int)f2bf(r1) << 16);
    }
}

// agg2f: one block per bucket.  acc = sum h2p[src]; a2 = dinv*(acc+self) in LDS;
// y = a2@W2 + b2; pooled over sorted batch runs; uniform-block fast path.
__global__ __launch_bounds__(TPB) void agg2f_kernel(
        const int* __restrict__ bucketed,
        const int* __restrict__ counts, const int* __restrict__ bsum,
        int E, int nblk, int nbuck,
        const unsigned short* __restrict__ h2p, const float* __restrict__ dinv,
        const float* __restrict__ W2, const float* __restrict__ b2,
        const int* __restrict__ batch, float* __restrict__ out, int N) {
    __shared__ float acc[NPB * 17];
    __shared__ float w2s[16 * 64];
    __shared__ float pool[64];
    int bk = blockIdx.x, t = threadIdx.x;
    int n0 = bk << BK_SHIFT;
    int nn = min(NPB, N - n0);
    int e0 = cbase_at(counts, bsum, bk * nblk);
    int e1 = (bk + 1 < nbuck) ? cbase_at(counts, bsum, (bk + 1) * nblk) : E;

    for (int i = t; i < NPB * 17; i += TPB) acc[i] = 0.f;
    for (int i = t; i < 16 * 64; i += TPB) w2s[i] = W2[i];
    if (t < 64) pool[t] = 0.f;
    __syncthreads();
    agg_edges(bucketed, h2p, acc, e0, e1, t);
    __syncthreads();

    // a2 into acc in place
    for (int i = t; i < nn * 8; i += TPB) {
        int m = i >> 3, q = i & 7;
        int c = n0 + m;
        float dc = dinv[c];
        unsigned int us = *(const unsigned int*)&h2p[(size_t)c * 16 + 2 * q];
        acc[m * 17 + 2 * q]     = dc * (acc[m * 17 + 2 * q]     + bf2f((unsigned short)(us & 0xffff)));
        acc[m * 17 + 2 * q + 1] = dc * (acc[m * 17 + 2 * q + 1] + bf2f((unsigned short)(us >> 16)));
    }
    __syncthreads();

    // matmul + pooling: wave w handles nodes [w*64, w*64+64), lane j = out dim
    int wave = t >> 6, j = t & 63;
    float w2reg[16];
#pragma unroll
    for (int k = 0; k < 16; ++k) w2reg[k] = w2s[k * 64 + j];
    float b2j = b2[j];
    int g0 = batch[n0];
    bool uniform = (batch[min(n0 + NPB - 1, N - 1)] == g0);

    float val = 0.f;
    int g_cur = -1;
#pragma unroll 1
    for (int mi = 0; mi < 64; ++mi) {
        int m = wave * 64 + mi;
        if (m >= nn) break;
        const float* ar = &acc[m * 17];
        float y = b2j;
#pragma unroll
        for (int k = 0; k < 16; ++k) y = fmaf(ar[k], w2reg[k], y);
        if (uniform) {
            val += y;
        } else {
            int g = batch[n0 + m];
            if (g != g_cur) {
                if (g_cur >= 0) atomicAdd(&out[(size_t)g_cur * 64 + j], val);
                val = 0.f;
                g_cur = g;
            }
            val += y;
        }
    }
    if (uniform) {
        atomicAdd(&pool[j], val);            // LDS, 4-way per address
        __syncthreads();
        if (t < 64) atomicAdd(&out[(size_t)g0 * 64 + t], pool[t]);
    } else {
        if (g_cur >= 0) atomicAdd(&out[(size_t)g_cur * 64 + j], val);
    }
}

static inline size_t align64(size_t v) { return (v + 63) & ~(size_t)63; }

extern "C" void kernel_launch(void* const* d_in, const int* in_sizes, int n_in,
                              void* d_out, int out_size, void* d_ws, size_t ws_size,
                              hipStream_t stream) {
    const float* x     = (const float*)d_in[0];
    const int*   ei    = (const int*)d_in[1];
    const int*   batch = (const int*)d_in[2];
    const float* W1    = (const float*)d_in[3];
    const float* b1    = (const float*)d_in[4];
    const float* W2    = (const float*)d_in[5];
    const float* b2    = (const float*)d_in[6];

    const int N = in_sizes[0] / 128;
    const int E = in_sizes[1] / 2;
    const int* row = ei;        // edge_index[0]
    const int* col = ei + E;    // edge_index[1]

    const int NBLK  = (E + CHUNK - 1) / CHUNK;       // 782
    const int NBUCK = (N + NPB - 1) / NPB;           // 782 (<=1024)
    const int L     = NBUCK * NBLK;                  // 611524
    const int NBS   = (L + TPB - 1) / TPB;           // 2389 (<=4096 for scan2)
    const int NBG   = (N + TPB - 1) / TPB;           // 782

    char* p = (char*)d_ws;
    int*            counts   = (int*)p;            p += align64((size_t)L * 4);
    int*            bsum     = (int*)p;            p += align64(4096 * 4);
    int*            bucketed = (int*)p;            p += align64((size_t)E * 4);
    float*          dinv     = (float*)p;          p += align64((size_t)N * 4);
    unsigned short* h1b      = (unsigned short*)p; p += align64((size_t)N * 16 * 2);
    unsigned short* h1p      = (unsigned short*)p; p += align64((size_t)N * 16 * 2);
    unsigned short* h2p      = (unsigned short*)p; p += align64((size_t)N * 16 * 2);
    float*          out      = (float*)d_out;

    hipMemsetAsync(out, 0, (size_t)out_size * sizeof(float), stream);

    hist_kernel<<<NBLK, TPB, 0, stream>>>(col, counts, E, NBLK, NBUCK);
    scan1_kernel<<<NBS, TPB, 0, stream>>>(counts, bsum, L);
    scan2_kernel<<<1, 1024, 0, stream>>>(bsum, NBS);
    s1c_gemm_kernel<<<NBLK + NBG, TPB, 0, stream>>>(row, col, counts, bsum,
                                                    E, NBLK, NBUCK,
                                                    bucketed, x, W1, h1b, N, NBG);
    degscale_kernel<<<NBUCK, TPB, 0, stream>>>(bucketed, counts, bsum, E, NBLK, NBUCK,
                                               dinv, h1b, h1p, N);
    agg1_kernel<<<NBUCK, TPB, 0, stream>>>(bucketed, counts, bsum, E, NBLK, NBUCK,
                                           h1p, dinv, b1, h2p, N);
    agg2f_kernel<<<NBUCK, TPB, 0, stream>>>(bucketed, counts, bsum, E, NBLK, NBUCK,
                                            h2p, dinv, W2, b2, batch, out, N);
}